// Round 7
// baseline (247.966 us; speedup 1.0000x reference)
//
#include <hip/hip_runtime.h>
#include <math.h>

// Problem constants: IN_DIM=128, HEADS=8, HEAD_DIM=16, HEADS*HEAD_DIM=128.
#define DIM 128
#define N_HEADS 8
#define HD 16
#define CAP 64   // bucket capacity (deg ~Poisson(16); P(>64)~3e-22)

typedef __attribute__((ext_vector_type(8))) short bf16x8;   // MFMA A/B frag (4 VGPRs)
typedef __attribute__((ext_vector_type(4))) float f32x4;    // MFMA C/D frag

// ---------------------------------------------------------------------------
// bf16 helpers (RNE pack, cheap unpack)
// ---------------------------------------------------------------------------
__device__ __forceinline__ unsigned bf16pack2(float a, float b) {
    unsigned ua = __builtin_bit_cast(unsigned, a);
    unsigned ub = __builtin_bit_cast(unsigned, b);
    ua = (ua + 0x7FFFu + ((ua >> 16) & 1u)) >> 16;
    ub = (ub + 0x7FFFu + ((ub >> 16) & 1u)) >> 16;
    return ua | (ub << 16);
}
__device__ __forceinline__ float bf16lo(unsigned p) {
    return __builtin_bit_cast(float, p << 16);
}
__device__ __forceinline__ float bf16hi(unsigned p) {
    return __builtin_bit_cast(float, p & 0xFFFF0000u);
}

// ---------------------------------------------------------------------------
// Init: zero cnt (blocks [0,NB)) || convert W -> WT/bias384 (blocks >= NB).
// ---------------------------------------------------------------------------
__global__ __launch_bounds__(256)
void init_kernel(const float* __restrict__ WQ, const float* __restrict__ bQ,
                 const float* __restrict__ WK, const float* __restrict__ bK,
                 const float* __restrict__ WV, const float* __restrict__ bV,
                 unsigned short* __restrict__ WT, float* __restrict__ bias384,
                 int* __restrict__ cnt, int NB, int N)
{
    if ((int)blockIdx.x < NB) {
        int i = blockIdx.x * 256 + threadIdx.x;
        if (i < N) cnt[i] = 0;
    } else {
        int idx = ((int)blockIdx.x - NB) * 256 + threadIdx.x;   // 0..49151
        int c = idx >> 7, k = idx & 127;
        const float* W; const float* b; int col = c & 127;
        if (c < 128)      { W = WQ; b = bQ; }
        else if (c < 256) { W = WK; b = bK; }
        else              { W = WV; b = bV; }
        float v = W[k * DIM + col];
        WT[(size_t)c * DIM + k] = (unsigned short)(bf16pack2(v, 0.0f) & 0xFFFFu);
        if (k == 0) bias384[c] = b[col];
    }
}

// ---------------------------------------------------------------------------
// Fused append + qkv. Append blocks FIRST.
// append: bucket entries stored SLOT-PERMUTED: slot s -> pos (s&3)*16+(s>>2),
//   so aggregate lane e4's 8 sequential pass-entries (edge = 4p+e4) are ONE
//   aligned uint4 (positions 16*e4 .. 16*e4+7).
// qkv: head-major outputs (round-6 layout, XCD sharding):
//   Qh [h][node]: 8 dwords (32B);  dword j = Q dims 2j,2j+1 of head h.
//   KVh[h][node]: 16 dwords (64B) = ONE cache line; dw 0-7 K, dw 8-15 V.
// ---------------------------------------------------------------------------
__global__ __launch_bounds__(256)
void append_qkv_kernel(const int* __restrict__ src, const int* __restrict__ dst,
                       int* __restrict__ cnt, unsigned short* __restrict__ srcsF,
                       int E, int EB,
                       const float* __restrict__ h,
                       const unsigned short* __restrict__ WT,
                       const float* __restrict__ bias384,
                       unsigned* __restrict__ Qh, unsigned* __restrict__ KVh,
                       int N)
{
    __shared__ unsigned short hs[64 * 136];

    if ((int)blockIdx.x < EB) {
        // ---- append phase (slot-permuted bucket positions) ---------------
        int t = (blockIdx.x * 256 + threadIdx.x) * 4;
        if (t + 3 < E) {
            int4 d4 = *(const int4*)(dst + t);
            int4 s4 = *(const int4*)(src + t);
            int sl0 = atomicAdd(&cnt[d4.x], 1);
            int sl1 = atomicAdd(&cnt[d4.y], 1);
            int sl2 = atomicAdd(&cnt[d4.z], 1);
            int sl3 = atomicAdd(&cnt[d4.w], 1);
            if (sl0 < CAP) srcsF[(size_t)d4.x * CAP + ((sl0 & 3) * 16 + (sl0 >> 2))] = (unsigned short)s4.x;
            if (sl1 < CAP) srcsF[(size_t)d4.y * CAP + ((sl1 & 3) * 16 + (sl1 >> 2))] = (unsigned short)s4.y;
            if (sl2 < CAP) srcsF[(size_t)d4.z * CAP + ((sl2 & 3) * 16 + (sl2 >> 2))] = (unsigned short)s4.z;
            if (sl3 < CAP) srcsF[(size_t)d4.w * CAP + ((sl3 & 3) * 16 + (sl3 >> 2))] = (unsigned short)s4.w;
        } else {
            for (int e = t; e < E; ++e) {
                int d    = dst[e];
                int slot = atomicAdd(&cnt[d], 1);
                if (slot < CAP)
                    srcsF[(size_t)d * CAP + ((slot & 3) * 16 + (slot >> 2))] = (unsigned short)src[e];
            }
        }
        return;
    }

    // ---- qkv phase ------------------------------------------------------
    const int tid = threadIdx.x;
    const int n0  = ((int)blockIdx.x - EB) * 64;

    #pragma unroll
    for (int i = 0; i < 4; ++i) {
        int lin  = i * 256 + tid;          // 0..1023
        int node = lin >> 4;               // 0..63
        int k0   = (lin & 15) * 8;         // 0..120
        int gn   = n0 + node;
        float4 a0, a1;
        if (gn < N) {
            a0 = *(const float4*)(h + (size_t)gn * DIM + k0);
            a1 = *(const float4*)(h + (size_t)gn * DIM + k0 + 4);
        } else {
            a0 = make_float4(0.f, 0.f, 0.f, 0.f);
            a1 = a0;
        }
        uint4 p = make_uint4(bf16pack2(a0.x, a0.y), bf16pack2(a0.z, a0.w),
                             bf16pack2(a1.x, a1.y), bf16pack2(a1.z, a1.w));
        *(uint4*)(hs + node * 136 + k0) = p;
    }
    __syncthreads();

    const int wave   = tid >> 6;
    const int l      = tid & 63;
    const int lane16 = l & 15;
    const int quad   = l >> 4;
    const int wc0    = wave * 96;

    f32x4 acc[6][4];
    #pragma unroll
    for (int ct = 0; ct < 6; ++ct) {
        float4 bv = *(const float4*)(bias384 + wc0 + ct * 16 + quad * 4);
        #pragma unroll
        for (int rt = 0; rt < 4; ++rt)
            acc[ct][rt] = (f32x4){bv.x, bv.y, bv.z, bv.w};
    }

    #pragma unroll
    for (int ks = 0; ks < 4; ++ks) {
        bf16x8 a[6], b[4];
        #pragma unroll
        for (int ct = 0; ct < 6; ++ct)
            a[ct] = *(const bf16x8*)(WT + (size_t)(wc0 + ct * 16 + lane16) * DIM
                                         + ks * 32 + quad * 8);
        #pragma unroll
        for (int rt = 0; rt < 4; ++rt)
            b[rt] = *(const bf16x8*)(hs + (rt * 16 + lane16) * 136 + ks * 32 + quad * 8);
        #pragma unroll
        for (int ct = 0; ct < 6; ++ct)
            #pragma unroll
            for (int rt = 0; rt < 4; ++rt)
                acc[ct][rt] = __builtin_amdgcn_mfma_f32_16x16x32_bf16(
                    a[ct], b[rt], acc[ct][rt], 0, 0, 0);
    }

    // ---- epilogue: head-major uint2 stores -------------------------------
    #pragma unroll
    for (int ct = 0; ct < 6; ++ct) {
        const int col = wc0 + ct * 16 + quad * 4;   // multiple of 4
        #pragma unroll
        for (int rt = 0; rt < 4; ++rt) {
            int gn = n0 + rt * 16 + lane16;
            if (gn >= N) continue;
            f32x4 v = acc[ct][rt];
            uint2 pr = make_uint2(bf16pack2(v[0], v[1]), bf16pack2(v[2], v[3]));
            if (col < 128) {
                int hq = col >> 4, d = col & 15;
                *(uint2*)(Qh + ((size_t)hq * N + gn) * 8 + (d >> 1)) = pr;
            } else if (col < 256) {
                int c = col - 128, hq = c >> 4, d = c & 15;
                *(uint2*)(KVh + ((size_t)hq * N + gn) * 16 + (d >> 1)) = pr;
            } else {
                int c = col - 256, hq = c >> 4, d = c & 15;
                *(uint2*)(KVh + ((size_t)hq * N + gn) * 16 + 8 + (d >> 1)) = pr;
            }
        }
    }
}

// ---------------------------------------------------------------------------
// Aggregate v5: head-sharded (1 head<->1 XCD, confirmed: FETCH 182->72MB) +
// FULLY-COALESCED gathers.
// Round-6 post-mortem: v4's 1-lane-per-line pattern = 4 line-requests per
// edge-head (25.6M total) -> vmem request-rate bound (~1.1 req/cyc/CU).
// v5: wave = 4 dsts (lane bits 4-5) x 4 edge slots (bits 2-3) x 4 quads
// (bits 0-1). The 4 quad-lanes of an edge load its 64B K||V line as 4
// consecutive dwordx4 -> 1 line-request per edge-head (6.4M total, 4x fewer).
//   quad0: K dims 0-7 | quad1: K dims 8-15 | quad2: V dims 0-7 | quad3: 8-15
//   dot = half-dot + shfl_xor(.,1); w broadcast to V-quads via shfl_xor(.,2);
//   slot-reduce = 2 shfl stages (masks 4, 8).
// Bucket: slot-permuted rows -> lane e4's pass-entries = one uint4 (passes
// 0-7, edge=4p+e4); second uint4 only when deg>32 (P~2e-4).
// Cross-group prefetch of (cnt, Q, bucket) keeps the chain 1-deep.
// ---------------------------------------------------------------------------
__global__ __launch_bounds__(256)
void aggregate_kernel(const int* __restrict__ cnt,
                      const unsigned short* __restrict__ srcsF,
                      const unsigned* __restrict__ Qh,
                      const unsigned* __restrict__ KVh,
                      float* __restrict__ out, int N)
{
    const int hh   = blockIdx.x & 7;                                  // head == XCD
    const int wseq = ((int)blockIdx.x >> 3) * 4 + (threadIdx.x >> 6); // 0..1023
    const int lane = threadIdx.x & 63;
    const int dloc = lane >> 4;         // 0..3  dst within group
    const int e4   = (lane >> 2) & 3;   // 0..3  edge slot
    const int quad = lane & 3;          // 0..3  16B chunk of the KV line
    const size_t hN = (size_t)hh * N;

    const int RUN   = (N + 1023) >> 10;                // 49
    const int start = wseq * RUN;
    if (start >= N) return;
    const int end   = (start + RUN < N) ? (start + RUN) : N;

    // ---- prologue: group 0 meta ------------------------------------------
    int myDst = start + dloc;
    int aD    = (myDst < end) ? myDst : start;
    int deg   = 0;
    if (myDst < end) { int d_ = cnt[aD]; deg = d_ > CAP ? CAP : d_; }
    uint4 qv = *(const uint4*)(Qh + (hN + aD) * 8 + (quad & 1) * 4);
    uint4 bk = *(const uint4*)(srcsF + (size_t)aD * CAP + e4 * 16);

    for (int d0 = start; d0 < end; d0 += 4) {
        myDst = d0 + dloc;
        aD    = (myDst < end) ? myDst : start;

        // ---- prefetch next group (flies under this group's work) ---------
        int ndeg = 0; uint4 nqv = qv, nbk = bk;
        const bool hasNext = (d0 + 4) < end;
        if (hasNext) {
            int nd = d0 + 4 + dloc;
            int na = (nd < end) ? nd : start;
            if (nd < end) { int d_ = cnt[na]; ndeg = d_ > CAP ? CAP : d_; }
            nqv = *(const uint4*)(Qh + (hN + na) * 8 + (quad & 1) * 4);
            nbk = *(const uint4*)(srcsF + (size_t)na * CAP + e4 * 16);
        }

        // ---- unpack this lane's Q half -----------------------------------
        float q[8];
        q[0] = bf16lo(qv.x); q[1] = bf16hi(qv.x);
        q[2] = bf16lo(qv.y); q[3] = bf16hi(qv.y);
        q[4] = bf16lo(qv.z); q[5] = bf16hi(qv.z);
        q[6] = bf16lo(qv.w); q[7] = bf16hi(qv.w);

        // ---- uniform pass count over the 4 dsts --------------------------
        int md = deg;
        md = max(md, __shfl_xor(md, 16));
        md = max(md, __shfl_xor(md, 32));
        const int npass = (md + 3) >> 2;
        const int np0   = npass < 8 ? npass : 8;

        float acc[8] = {0.f, 0.f, 0.f, 0.f, 0.f, 0.f, 0.f, 0.f};
        float z = 0.f;

        for (int p = 0; p < np0; ++p) {
            unsigned sw = (p & 4) ? ((p & 2) ? bk.w : bk.z)
                                  : ((p & 2) ? bk.y : bk.x);
            int s   = (int)((sw >> ((p & 1) * 16)) & 0xFFFFu);
            int e   = p * 4 + e4;
            bool val = e < deg;
            s = val ? s : 0;

            uint4 kv = *(const uint4*)(KVh + (hN + (size_t)s) * 16 + quad * 4);

            float pd = bf16lo(kv.x) * q[0] + bf16hi(kv.x) * q[1]
                     + bf16lo(kv.y) * q[2] + bf16hi(kv.y) * q[3]
                     + bf16lo(kv.z) * q[4] + bf16hi(kv.z) * q[5]
                     + bf16lo(kv.w) * q[6] + bf16hi(kv.w) * q[7];
            float dsum = pd + __shfl_xor(pd, 1);           // full dot on quads 0,1
            float pc = fminf(fmaxf(dsum * 0.25f, -5.0f), 5.0f);
            float w  = val ? __expf(pc) : 0.0f;
            float w2 = __shfl_xor(w, 2);                   // quad2<-0, quad3<-1
            w = (quad & 2) ? w2 : w;
            z += w;
            acc[0] += w * bf16lo(kv.x); acc[1] += w * bf16hi(kv.x);
            acc[2] += w * bf16lo(kv.y); acc[3] += w * bf16hi(kv.y);
            acc[4] += w * bf16lo(kv.z); acc[5] += w * bf16hi(kv.z);
            acc[6] += w * bf16lo(kv.w); acc[7] += w * bf16hi(kv.w);
        }

        if (npass > 8) {            // deg>32 somewhere: rare (P~2e-4)
            uint4 bk1 = *(const uint4*)(srcsF + (size_t)aD * CAP + e4 * 16 + 8);
            for (int p = 8; p < npass; ++p) {
                int pl = p - 8;
                unsigned sw = (pl & 4) ? ((pl & 2) ? bk1.w : bk1.z)
                                       : ((pl & 2) ? bk1.y : bk1.x);
                int s   = (int)((sw >> ((pl & 1) * 16)) & 0xFFFFu);
                int e   = p * 4 + e4;
                bool val = e < deg;
                s = val ? s : 0;

                uint4 kv = *(const uint4*)(KVh + (hN + (size_t)s) * 16 + quad * 4);
                float pd = bf16lo(kv.x) * q[0] + bf16hi(kv.x) * q[1]
                         + bf16lo(kv.y) * q[2] + bf16hi(kv.y) * q[3]
                         + bf16lo(kv.z) * q[4] + bf16hi(kv.z) * q[5]
                         + bf16lo(kv.w) * q[6] + bf16hi(kv.w) * q[7];
                float dsum = pd + __shfl_xor(pd, 1);
                float pc = fminf(fmaxf(dsum * 0.25f, -5.0f), 5.0f);
                float w  = val ? __expf(pc) : 0.0f;
                float w2 = __shfl_xor(w, 2);
                w = (quad & 2) ? w2 : w;
                z += w;
                acc[0] += w * bf16lo(kv.x); acc[1] += w * bf16hi(kv.x);
                acc[2] += w * bf16lo(kv.y); acc[3] += w * bf16hi(kv.y);
                acc[4] += w * bf16lo(kv.z); acc[5] += w * bf16hi(kv.z);
                acc[6] += w * bf16lo(kv.w); acc[7] += w * bf16hi(kv.w);
            }
        }

        // ---- reduce over edge slots (lane bits 2-3) ----------------------
        #pragma unroll
        for (int m = 4; m <= 8; m <<= 1) {
            z += __shfl_xor(z, m);
            #pragma unroll
            for (int k = 0; k < 8; ++k) acc[k] += __shfl_xor(acc[k], m);
        }

        if (e4 == 0 && (quad & 2) && myDst < end) {
            float inv = (z > 0.0f) ? (1.0f / z) : 0.0f;
            float* op = out + (size_t)myDst * DIM + hh * HD + (quad & 1) * 8;
            f32x4 o0 = {acc[0] * inv, acc[1] * inv, acc[2] * inv, acc[3] * inv};
            f32x4 o1 = {acc[4] * inv, acc[5] * inv, acc[6] * inv, acc[7] * inv};
            __builtin_nontemporal_store(o0, (f32x4*)(op));
            __builtin_nontemporal_store(o1, (f32x4*)(op + 4));
        }

        // ---- rotate prefetched meta --------------------------------------
        deg = ndeg; qv = nqv; bk = nbk;
    }
}

// ---------------------------------------------------------------------------
extern "C" void kernel_launch(void* const* d_in, const int* in_sizes, int n_in,
                              void* d_out, int out_size, void* d_ws, size_t ws_size,
                              hipStream_t stream) {
    const float* h   = (const float*)d_in[0];
    const int*   src = (const int*)  d_in[1];
    const int*   dst = (const int*)  d_in[2];
    const float* WQ  = (const float*)d_in[3];
    const float* bQ  = (const float*)d_in[4];
    const float* WK  = (const float*)d_in[5];
    const float* bK  = (const float*)d_in[6];
    const float* WV  = (const float*)d_in[7];
    const float* bV  = (const float*)d_in[8];
    float* out = (float*)d_out;

    const int N  = in_sizes[0] / DIM;
    const int E  = in_sizes[1];
    const int NB = (N + 255) / 256;            // blocks to zero cnt
    const int EB = (E / 4 + 255) / 256;        // append blocks (4 edges/thread)
    const int QB = (N + 63) / 64;              // qkv blocks
    const int nConv = (384 * DIM) / 256;       // convert blocks

    // Workspace: Qh (12.8MB) | KVh (25.6MB) | WT (96KB) | bias384 | cnt (200KB)
    //            | srcsF (N*CAP*2 = 6.4MB)   -> ~45 MB total
    char* w = (char*)d_ws;
    unsigned*       Qh      = (unsigned*)w;        w += (size_t)N * 64  * sizeof(unsigned);
    unsigned*       KVh     = (unsigned*)w;        w += (size_t)N * 128 * sizeof(unsigned);
    unsigned short* WT      = (unsigned short*)w;  w += (size_t)384 * DIM * sizeof(unsigned short);
    float*          bias384 = (float*)w;           w += 384 * sizeof(float);
    int*            cnt     = (int*)w;             w += (size_t)N * sizeof(int);
    unsigned short* srcsF   = (unsigned short*)w;

    init_kernel<<<NB + nConv, 256, 0, stream>>>(WQ, bQ, WK, bK, WV, bV,
                                                WT, bias384, cnt, NB, N);
    append_qkv_kernel<<<EB + QB, 256, 0, stream>>>(src, dst, cnt, srcsF, E, EB,
                                                   h, WT, bias384, Qh, KVh, N);
    aggregate_kernel<<<2048, 256, 0, stream>>>(cnt, srcsF, Qh, KVh, out, N);
}

// Round 8
// 220.370 us; speedup vs baseline: 1.1252x; 1.1252x over previous
//
#include <hip/hip_runtime.h>
#include <math.h>

// Problem constants: IN_DIM=128, HEADS=8, HEAD_DIM=16, HEADS*HEAD_DIM=128.
#define DIM 128
#define N_HEADS 8
#define HD 16
#define CAP 64   // bucket capacity (deg ~Poisson(16); P(>64)~3e-22)

typedef __attribute__((ext_vector_type(8))) short bf16x8;   // MFMA A/B frag (4 VGPRs)
typedef __attribute__((ext_vector_type(4))) float f32x4;    // MFMA C/D frag

// ---------------------------------------------------------------------------
// bf16 helpers (RNE pack, cheap unpack)
// ---------------------------------------------------------------------------
__device__ __forceinline__ unsigned bf16pack2(float a, float b) {
    unsigned ua = __builtin_bit_cast(unsigned, a);
    unsigned ub = __builtin_bit_cast(unsigned, b);
    ua = (ua + 0x7FFFu + ((ua >> 16) & 1u)) >> 16;
    ub = (ub + 0x7FFFu + ((ub >> 16) & 1u)) >> 16;
    return ua | (ub << 16);
}
__device__ __forceinline__ float bf16lo(unsigned p) {
    return __builtin_bit_cast(float, p << 16);
}
__device__ __forceinline__ float bf16hi(unsigned p) {
    return __builtin_bit_cast(float, p & 0xFFFF0000u);
}

// ---------------------------------------------------------------------------
// Init: zero cnt (blocks [0,NB)) || convert W -> WT/bias384 (blocks >= NB).
// ---------------------------------------------------------------------------
__global__ __launch_bounds__(256)
void init_kernel(const float* __restrict__ WQ, const float* __restrict__ bQ,
                 const float* __restrict__ WK, const float* __restrict__ bK,
                 const float* __restrict__ WV, const float* __restrict__ bV,
                 unsigned short* __restrict__ WT, float* __restrict__ bias384,
                 int* __restrict__ cnt, int NB, int N)
{
    if ((int)blockIdx.x < NB) {
        int i = blockIdx.x * 256 + threadIdx.x;
        if (i < N) cnt[i] = 0;
    } else {
        int idx = ((int)blockIdx.x - NB) * 256 + threadIdx.x;   // 0..49151
        int c = idx >> 7, k = idx & 127;
        const float* W; const float* b; int col = c & 127;
        if (c < 128)      { W = WQ; b = bQ; }
        else if (c < 256) { W = WK; b = bK; }
        else              { W = WV; b = bV; }
        float v = W[k * DIM + col];
        WT[(size_t)c * DIM + k] = (unsigned short)(bf16pack2(v, 0.0f) & 0xFFFFu);
        if (k == 0) bias384[c] = b[col];
    }
}

// ---------------------------------------------------------------------------
// Fused append + qkv.
//
// APPEND (round-8 redesign): XCD-SHARDED atomics. Round-7 counters showed
// aq WRITE_SIZE=84MB (qkv accounts for 38) with all pipes idle: scattered
// cross-XCD RMWs on cnt/srcsF bounce each 64B line ~8x between private L2s
// (writeback+refetch per bounce) and serialize on coherence. Fix = same
// blockIdx&7 XCD mapping that provably collapsed FETCH in round 6:
//   block bid scans edge window (bid>>3)*4096 (coalesced int4) and appends
//   ONLY edges with dst&7 == bid&7 -> each cnt/srcsF line owned by ONE XCD:
//   L2-resident accumulation, evict-once. Cost: 8x re-read of src/dst
//   (6.4MB arrays, L3-resident after first pass).
// srcsF: plain slot order, ushort entries (N < 65536).
//
// QKV: unchanged (round-2 node-major layouts).
//   Qd row n: 64 dwords (256B), dword j = Q dims 2j,2j+1.
//   KVd row n: 128 dwords (512B), chunk c in [0,16): dwords 8c..8c+3 = K dims
//   8c..8c+7, dwords 8c+4..8c+7 = V dims 8c..8c+7.
// ---------------------------------------------------------------------------
__global__ __launch_bounds__(256)
void append_qkv_kernel(const int* __restrict__ src, const int* __restrict__ dst,
                       int* __restrict__ cnt, unsigned short* __restrict__ srcsF,
                       int E, int AB,
                       const float* __restrict__ h,
                       const unsigned short* __restrict__ WT,
                       const float* __restrict__ bias384,
                       unsigned* __restrict__ Qd, unsigned* __restrict__ KVd,
                       int N)
{
    __shared__ unsigned short hs[64 * 136];

    if ((int)blockIdx.x < AB) {
        // ---- append phase: shard = XCD, window scan ----------------------
        const int shard = blockIdx.x & 7;
        const int w0    = ((int)blockIdx.x >> 3) * 4096;
        #pragma unroll
        for (int it = 0; it < 4; ++it) {
            int e0 = w0 + (it * 256 + (int)threadIdx.x) * 4;
            if (e0 + 3 < E) {
                int4 d4 = *(const int4*)(dst + e0);
                int4 s4 = *(const int4*)(src + e0);
                if ((d4.x & 7) == shard) {
                    int sl = atomicAdd(&cnt[d4.x], 1);
                    if (sl < CAP) srcsF[(size_t)d4.x * CAP + sl] = (unsigned short)s4.x;
                }
                if ((d4.y & 7) == shard) {
                    int sl = atomicAdd(&cnt[d4.y], 1);
                    if (sl < CAP) srcsF[(size_t)d4.y * CAP + sl] = (unsigned short)s4.y;
                }
                if ((d4.z & 7) == shard) {
                    int sl = atomicAdd(&cnt[d4.z], 1);
                    if (sl < CAP) srcsF[(size_t)d4.z * CAP + sl] = (unsigned short)s4.z;
                }
                if ((d4.w & 7) == shard) {
                    int sl = atomicAdd(&cnt[d4.w], 1);
                    if (sl < CAP) srcsF[(size_t)d4.w * CAP + sl] = (unsigned short)s4.w;
                }
            } else {
                for (int e = e0; e < E && e < e0 + 4; ++e) {
                    int d = dst[e];
                    if ((d & 7) == shard) {
                        int sl = atomicAdd(&cnt[d], 1);
                        if (sl < CAP) srcsF[(size_t)d * CAP + sl] = (unsigned short)src[e];
                    }
                }
            }
        }
        return;
    }

    // ---- qkv phase ------------------------------------------------------
    const int tid = threadIdx.x;
    const int n0  = ((int)blockIdx.x - AB) * 64;

    #pragma unroll
    for (int i = 0; i < 4; ++i) {
        int lin  = i * 256 + tid;          // 0..1023
        int node = lin >> 4;               // 0..63
        int k0   = (lin & 15) * 8;         // 0..120
        int gn   = n0 + node;
        float4 a0, a1;
        if (gn < N) {
            a0 = *(const float4*)(h + (size_t)gn * DIM + k0);
            a1 = *(const float4*)(h + (size_t)gn * DIM + k0 + 4);
        } else {
            a0 = make_float4(0.f, 0.f, 0.f, 0.f);
            a1 = a0;
        }
        uint4 p = make_uint4(bf16pack2(a0.x, a0.y), bf16pack2(a0.z, a0.w),
                             bf16pack2(a1.x, a1.y), bf16pack2(a1.z, a1.w));
        *(uint4*)(hs + node * 136 + k0) = p;
    }
    __syncthreads();

    const int wave   = tid >> 6;
    const int l      = tid & 63;
    const int lane16 = l & 15;
    const int quad   = l >> 4;
    const int wc0    = wave * 96;

    f32x4 acc[6][4];
    #pragma unroll
    for (int ct = 0; ct < 6; ++ct) {
        float4 bv = *(const float4*)(bias384 + wc0 + ct * 16 + quad * 4);
        #pragma unroll
        for (int rt = 0; rt < 4; ++rt)
            acc[ct][rt] = (f32x4){bv.x, bv.y, bv.z, bv.w};
    }

    #pragma unroll
    for (int ks = 0; ks < 4; ++ks) {
        bf16x8 a[6], b[4];
        #pragma unroll
        for (int ct = 0; ct < 6; ++ct)
            a[ct] = *(const bf16x8*)(WT + (size_t)(wc0 + ct * 16 + lane16) * DIM
                                         + ks * 32 + quad * 8);
        #pragma unroll
        for (int rt = 0; rt < 4; ++rt)
            b[rt] = *(const bf16x8*)(hs + (rt * 16 + lane16) * 136 + ks * 32 + quad * 8);
        #pragma unroll
        for (int ct = 0; ct < 6; ++ct)
            #pragma unroll
            for (int rt = 0; rt < 4; ++rt)
                acc[ct][rt] = __builtin_amdgcn_mfma_f32_16x16x32_bf16(
                    a[ct], b[rt], acc[ct][rt], 0, 0, 0);
    }

    // ---- epilogue: node-major uint2 stores (round-2 layout) --------------
    #pragma unroll
    for (int ct = 0; ct < 6; ++ct) {
        const int col = wc0 + ct * 16 + quad * 4;   // multiple of 4
        #pragma unroll
        for (int rt = 0; rt < 4; ++rt) {
            int gn = n0 + rt * 16 + lane16;
            if (gn >= N) continue;
            f32x4 v = acc[ct][rt];
            uint2 pr = make_uint2(bf16pack2(v[0], v[1]), bf16pack2(v[2], v[3]));
            if (col < 128) {
                *(uint2*)(Qd + (size_t)gn * 64 + (col >> 1)) = pr;
            } else if (col < 256) {
                int c = col - 128;
                *(uint2*)(KVd + (size_t)gn * 128 + ((c >> 3) * 8) + ((c & 4) >> 1)) = pr;
            } else {
                int c = col - 256;
                *(uint2*)(KVd + (size_t)gn * 128 + ((c >> 3) * 8) + 4 + ((c & 4) >> 1)) = pr;
            }
        }
    }
}

// ---------------------------------------------------------------------------
// Aggregate: EXACT round-2 v2 structure (62us, best of 6 structures tried),
// with node enumeration aligned to append's XCD shards: block bid (XCD bid&7)
// processes nodes n ≡ bid&7 (mod 8), so cnt/srcsF reads hit the same XCD L2
// that append just wrote. Everything else verbatim from round 2.
// Wave = one dst node, 4 edge slots, 16 lanes/edge (c = l&15 -> dims c*8..+7).
// ---------------------------------------------------------------------------
__device__ __forceinline__ void agg_chunk16(
    const unsigned* __restrict__ KVd, int eg, int deg, int slot, int c,
    const int* raw,
    float q0, float q1, float q2, float q3,
    float q4, float q5, float q6, float q7,
    float acc[8], float& zs)
{
    bool val[4];
    const uint4* p[4];
    #pragma unroll
    for (int j = 0; j < 4; ++j) {
        int ee = eg + j * 4 + slot;
        val[j] = ee < deg;
        int s  = val[j] ? raw[j] : 0;
        p[j]   = (const uint4*)(KVd + (size_t)s * 128 + c * 8);
    }
    uint4 K[4], V[4];
    #pragma unroll
    for (int j = 0; j < 4; ++j) { K[j] = p[j][0]; V[j] = p[j][1]; }

    float d[4];
    #pragma unroll
    for (int j = 0; j < 4; ++j)
        d[j] = bf16lo(K[j].x) * q0 + bf16hi(K[j].x) * q1
             + bf16lo(K[j].y) * q2 + bf16hi(K[j].y) * q3
             + bf16lo(K[j].z) * q4 + bf16hi(K[j].z) * q5
             + bf16lo(K[j].w) * q6 + bf16hi(K[j].w) * q7;
    #pragma unroll
    for (int j = 0; j < 4; ++j) d[j] += __shfl_xor(d[j], 1);

    #pragma unroll
    for (int j = 0; j < 4; ++j) {
        float pc = fminf(fmaxf(d[j] * 0.25f, -5.0f), 5.0f);
        float w  = ((eg + j * 4 + slot) < deg) ? __expf(pc) : 0.0f;
        zs += w;
        acc[0] += w * bf16lo(V[j].x); acc[1] += w * bf16hi(V[j].x);
        acc[2] += w * bf16lo(V[j].y); acc[3] += w * bf16hi(V[j].y);
        acc[4] += w * bf16lo(V[j].z); acc[5] += w * bf16hi(V[j].z);
        acc[6] += w * bf16lo(V[j].w); acc[7] += w * bf16hi(V[j].w);
    }
}

__global__ __launch_bounds__(256, 4)
void aggregate_kernel(const int* __restrict__ cnt,
                      const unsigned short* __restrict__ srcsF,
                      const unsigned* __restrict__ Qd,
                      const unsigned* __restrict__ KVd,
                      float* __restrict__ out, int N)
{
    const int l    = threadIdx.x & 63;
    const int slot = l >> 4;
    const int c    = l & 15;
    const int xcd  = blockIdx.x & 7;
    const int widx = ((int)blockIdx.x >> 3) * 4 + (threadIdx.x >> 6);  // 0..1023
    const int STR  = 8 * 1024;      // node stride per pipeline step

    int node = xcd + 8 * widx;      // node ≡ xcd (mod 8)
    if (node >= N) return;

    // prime the pipeline: current node's deg, Q row, first 32 bucket slots
    int   deg = cnt[node];
    uint4 qd  = *(const uint4*)(Qd + (size_t)node * 64 + c * 4);
    int   pb[8];
    {
        const unsigned short* b = srcsF + (size_t)node * CAP;
        #pragma unroll
        for (int j = 0; j < 8; ++j)
            pb[j] = b[((j >> 2) << 4) + ((j & 3) << 2) + slot];   // ee 0..31
    }

    for (;;) {
        const int  nnode   = node + STR;
        const bool hasNext = nnode < N;

        // ---- prefetch next node (independent loads, hide under compute) --
        int ndeg = 0; uint4 nqd = make_uint4(0u, 0u, 0u, 0u); int npb[8];
        #pragma unroll
        for (int j = 0; j < 8; ++j) npb[j] = 0;
        if (hasNext) {
            ndeg = cnt[nnode];
            nqd  = *(const uint4*)(Qd + (size_t)nnode * 64 + c * 4);
            const unsigned short* b = srcsF + (size_t)nnode * CAP;
            #pragma unroll
            for (int j = 0; j < 8; ++j)
                npb[j] = b[((j >> 2) << 4) + ((j & 3) << 2) + slot];
        }

        // ---- process current node ---------------------------------------
        int degc = deg > CAP ? CAP : deg;
        const float q0 = bf16lo(qd.x), q1 = bf16hi(qd.x);
        const float q2 = bf16lo(qd.y), q3 = bf16hi(qd.y);
        const float q4 = bf16lo(qd.z), q5 = bf16hi(qd.z);
        const float q6 = bf16lo(qd.w), q7 = bf16hi(qd.w);

        float acc[8] = {0.f, 0.f, 0.f, 0.f, 0.f, 0.f, 0.f, 0.f};
        float zs = 0.f;

        if (degc > 0)
            agg_chunk16(KVd, 0, degc, slot, c, pb,
                        q0, q1, q2, q3, q4, q5, q6, q7, acc, zs);
        if (degc > 16)
            agg_chunk16(KVd, 16, degc, slot, c, pb + 4,
                        q0, q1, q2, q3, q4, q5, q6, q7, acc, zs);
        for (int eg = 32; eg < degc; eg += 16) {       // rare tail (deg > 32)
            int raw[4];
            const unsigned short* b = srcsF + (size_t)node * CAP;
            #pragma unroll
            for (int j = 0; j < 4; ++j) {
                int ee = eg + j * 4 + slot;
                raw[j] = b[ee < degc ? ee : 0];
            }
            agg_chunk16(KVd, eg, degc, slot, c, raw,
                        q0, q1, q2, q3, q4, q5, q6, q7, acc, zs);
        }

        // ---- cross-slot reduce (slots live in lane bits 4-5) ------------
        #pragma unroll
        for (int j = 0; j < 8; ++j) {
            acc[j] += __shfl_xor(acc[j], 16);
            acc[j] += __shfl_xor(acc[j], 32);
        }
        zs += __shfl_xor(zs, 16);
        zs += __shfl_xor(zs, 32);

        if (slot == 0) {
            float inv = (zs > 0.0f) ? (1.0f / zs) : 0.0f;
            f32x4 o0 = {acc[0] * inv, acc[1] * inv, acc[2] * inv, acc[3] * inv};
            f32x4 o1 = {acc[4] * inv, acc[5] * inv, acc[6] * inv, acc[7] * inv};
            __builtin_nontemporal_store(o0, (f32x4*)(out + (size_t)node * DIM + c * 8));
            __builtin_nontemporal_store(o1, (f32x4*)(out + (size_t)node * DIM + c * 8 + 4));
        }

        if (!hasNext) break;
        node = nnode; deg = ndeg; qd = nqd;
        #pragma unroll
        for (int j = 0; j < 8; ++j) pb[j] = npb[j];
    }
}

// ---------------------------------------------------------------------------
extern "C" void kernel_launch(void* const* d_in, const int* in_sizes, int n_in,
                              void* d_out, int out_size, void* d_ws, size_t ws_size,
                              hipStream_t stream) {
    const float* h   = (const float*)d_in[0];
    const int*   src = (const int*)  d_in[1];
    const int*   dst = (const int*)  d_in[2];
    const float* WQ  = (const float*)d_in[3];
    const float* bQ  = (const float*)d_in[4];
    const float* WK  = (const float*)d_in[5];
    const float* bK  = (const float*)d_in[6];
    const float* WV  = (const float*)d_in[7];
    const float* bV  = (const float*)d_in[8];
    float* out = (float*)d_out;

    const int N  = in_sizes[0] / DIM;
    const int E  = in_sizes[1];
    const int NB = (N + 255) / 256;            // blocks to zero cnt
    const int NW = (E + 4095) / 4096;          // append windows
    const int AB = NW * 8;                     // append blocks (window x shard)
    const int QB = (N + 63) / 64;              // qkv blocks
    const int nConv = (384 * DIM) / 256;       // convert blocks

    // Workspace: Qd (12.8MB) | KVd (25.6MB) | WT (96KB) | bias384 | cnt (200KB)
    //            | srcsF (N*CAP*2 = 6.4MB)   -> ~45 MB total
    char* w = (char*)d_ws;
    unsigned*       Qd      = (unsigned*)w;        w += (size_t)N * 64  * sizeof(unsigned);
    unsigned*       KVd     = (unsigned*)w;        w += (size_t)N * 128 * sizeof(unsigned);
    unsigned short* WT      = (unsigned short*)w;  w += (size_t)384 * DIM * sizeof(unsigned short);
    float*          bias384 = (float*)w;           w += 384 * sizeof(float);
    int*            cnt     = (int*)w;             w += (size_t)N * sizeof(int);
    unsigned short* srcsF   = (unsigned short*)w;

    init_kernel<<<NB + nConv, 256, 0, stream>>>(WQ, bQ, WK, bK, WV, bV,
                                                WT, bias384, cnt, NB, N);
    append_qkv_kernel<<<AB + QB, 256, 0, stream>>>(src, dst, cnt, srcsF, E, AB,
                                                   h, WT, bias384, Qd, KVd, N);
    aggregate_kernel<<<2048, 256, 0, stream>>>(cnt, srcsF, Qd, KVd, out, N);
}